// Round 4
// baseline (1159.549 us; speedup 1.0000x reference)
//
#include <hip/hip_runtime.h>
#include <stdint.h>

#define N_NODES 50000
#define N_EDGES 1600000
#define HID 128
#define NB 196      // dst buckets of 256 nodes
#define CHUNK 8192
#define NCH 196     // ceil(1600000 / 8192)
#define TOT (NB * NCH)
#define SCAN_J 152  // ceil(TOT/256)

typedef float f32x4 __attribute__((ext_vector_type(4)));
typedef short s16x8 __attribute__((ext_vector_type(8)));

__device__ __forceinline__ unsigned short f2bf(float f) {
  unsigned u = __float_as_uint(f);
  u += 0x7fffu + ((u >> 16) & 1u);   // RNE
  return (unsigned short)(u >> 16);
}

// ---- W transpose + convert: Wt[l][r][k][d] = W[l][r][d][k] (r=8 -> W_loop) ----
__global__ void k_convert_w(const float* __restrict__ W, const float* __restrict__ Wl,
                            unsigned short* __restrict__ Wt) {
  int idx = blockIdx.x * 256 + threadIdx.x;   // (((l*9+r)*128)+k)*128+d
  int d  = idx & 127;
  int k  = (idx >> 7) & 127;
  int lr = idx >> 14;                          // l*9 + r
  int l = lr / 9, r = lr - l * 9;
  float v;
  if (r < 8) v = W[((((size_t)l * 8 + r) * 128) + d) * 128 + k];
  else       v = Wl[(((size_t)l * 128) + d) * 128 + k];
  Wt[idx] = f2bf(v);
}

// ---- h0 = bf16(emb[node_id]) ----
__global__ void k_gather_h0(const int* __restrict__ nid, const float* __restrict__ emb,
                            unsigned short* __restrict__ h0) {
  int t = blockIdx.x * 256 + threadIdx.x;      // N*32 threads, 4 elems each
  int i = t >> 5, c = (t & 31) * 4;
  if (i >= N_NODES) return;
  const float4 v = *(const float4*)(emb + (size_t)nid[i] * HID + c);
  ushort4 o;
  o.x = f2bf(v.x); o.y = f2bf(v.y); o.z = f2bf(v.z); o.w = f2bf(v.w);
  *(ushort4*)(h0 + (size_t)i * HID + c) = o;
}

__device__ __forceinline__ int block_scan_excl(int v, int t) {
  const int lane = t & 63, wid = t >> 6;
  int incl = v;
  #pragma unroll
  for (int o = 1; o < 64; o <<= 1) {
    int nv = __shfl_up(incl, o);
    if (lane >= o) incl += nv;
  }
  __shared__ int wsum[4];
  if (lane == 63) wsum[wid] = incl;
  __syncthreads();
  int wbase = 0;
  #pragma unroll
  for (int w = 0; w < 3; ++w) if (w < wid) wbase += wsum[w];
  return wbase + incl - v;
}

// ---- CSR pass A: per-chunk bucket histogram -> TRANSPOSED store histT[b][c] ----
__global__ void k_chunk_hist(const int* __restrict__ dst, int* __restrict__ histT) {
  __shared__ int h[NB];
  const int c = blockIdx.x, t = threadIdx.x;
  if (t < NB) h[t] = 0;
  __syncthreads();
  int base = c * CHUNK;
  #pragma unroll 4
  for (int i = t; i < CHUNK; i += 256) {
    int e = base + i;
    if (e < N_EDGES) atomicAdd(&h[dst[e] >> 8], 1);
  }
  __syncthreads();
  if (t < NB) histT[t * NCH + c] = h[t];
}

// ---- CSR pass B: scan 38416 counters (contiguous in bucket-major layout) ----
__global__ void k_csr_scan(const int* __restrict__ histT, int* __restrict__ cur,
                           int* __restrict__ bbase, int* __restrict__ rowptr2) {
  const int t = threadIdx.x;
  const int lo = t * SCAN_J;
  int s = 0;
  #pragma unroll 8
  for (int j = 0; j < SCAN_J; ++j) {
    int idx = lo + j;
    if (idx < TOT) s += histT[idx];
  }
  int run = block_scan_excl(s, t);
  #pragma unroll 4
  for (int j = 0; j < SCAN_J; ++j) {
    int idx = lo + j;                    // idx = b*NCH + c
    if (idx < TOT) {
      int b = idx / NCH, c = idx - b * NCH;
      cur[c * NB + b] = run;
      if (c == 0) bbase[b] = run;
      run += histT[idx];
    }
  }
  if (t == 0) { bbase[NB] = N_EDGES; rowptr2[(size_t)N_NODES * 8] = N_EDGES; }
}

// ---- CSR pass C: chunk-local scatter via LDS cursors (no global atomics) ----
// record = (dst&255)<<19 | et<<16 | src
__global__ void k_chunk_scatter(const int* __restrict__ src, const int* __restrict__ dst,
                                const int* __restrict__ et, const int* __restrict__ cur,
                                unsigned* __restrict__ tmp) {
  __shared__ int off2[NB];
  const int c = blockIdx.x, t = threadIdx.x;
  if (t < NB) off2[t] = cur[c * NB + t];
  __syncthreads();
  int base = c * CHUNK;
  #pragma unroll 4
  for (int i = t; i < CHUNK; i += 256) {
    int e = base + i;
    if (e < N_EDGES) {
      int d = dst[e];
      int pos = atomicAdd(&off2[d >> 8], 1);
      tmp[pos] = ((unsigned)(d & 255) << 19) | ((unsigned)et[e] << 16) | (unsigned)src[e];
    }
  }
}

// ---- CSR finalize: per-(node,rel) counting sort -> rowptr2 + ushort keys ----
__global__ void k_bucket_finalize(const unsigned* __restrict__ tmp,
                                  const int* __restrict__ bbase,
                                  int* __restrict__ rowptr2,
                                  unsigned short* __restrict__ keys) {
  __shared__ int cnt2[2048];
  __shared__ int off2[2048];
  const int b = blockIdx.x;
  const int t = threadIdx.x;
  const int s = bbase[b], e = bbase[b + 1];
  for (int i = t; i < 2048; i += 256) cnt2[i] = 0;
  __syncthreads();
  for (int i = s + t; i < e; i += 256) {
    unsigned r = tmp[i];
    atomicAdd(&cnt2[((r >> 19) & 255u) * 8 + ((r >> 16) & 7u)], 1);
  }
  __syncthreads();
  int v8[8]; int sum = 0;
  #pragma unroll
  for (int j = 0; j < 8; ++j) { v8[j] = cnt2[t * 8 + j]; sum += v8[j]; }
  int ex = block_scan_excl(sum, t);
  int run = s + ex;
  int node = b * 256 + t;
  #pragma unroll
  for (int j = 0; j < 8; ++j) {
    if (node < N_NODES) rowptr2[(size_t)node * 8 + j] = run;
    off2[t * 8 + j] = run;
    run += v8[j];
  }
  __syncthreads();
  for (int i = s + t; i < e; i += 256) {
    unsigned r = tmp[i];
    int pos = atomicAdd(&off2[((r >> 19) & 255u) * 8 + ((r >> 16) & 7u)], 1);
    keys[pos] = (unsigned short)(r & 0xffffu);
  }
}

// ---- fused layer: per-(node,rel) aggregate of h[src] -> MFMA with W_r, all rels ----
// out[v][k] = sum_r ( sum_{e in seg(v,r)} h[src_e] ) @ Wt_r  + h[v] @ Wt_8 + bias
template <bool LAST>
__global__ __launch_bounds__(256, 3) void k_layer(
    const unsigned short* __restrict__ h,     // [N][128] bf16
    const unsigned short* __restrict__ keys,  // [E] u16 src
    const int* __restrict__ rowptr2,          // [N*8+1]
    const unsigned short* __restrict__ Wt,    // [9][128][128] bf16 (this layer)
    const float* __restrict__ bias,           // [128]
    void* __restrict__ out) {
  __shared__ unsigned char As[64 * 256];      // 16KB: 64 nodes x 128 bf16 (swizzled)
  __shared__ unsigned char Bs[128 * 256];     // 32KB: W_r tile (swizzled)
  const int t = threadIdx.x, wid = t >> 6, lane = t & 63;
  const int nb = blockIdx.x * 64;
  const int lr = lane & 15, kg = (lane >> 4) * 8;
  const unsigned char* hB = (const unsigned char*)h;
  f32x4 C[8];
  #pragma unroll
  for (int n = 0; n < 8; ++n) C[n] = (f32x4)(0.f);

  for (int r = 0; r < 9; ++r) {
    // stage W_r (32KB), 16B-granule XOR swizzle byte^((row&7)<<4)
    const unsigned char* Bsrc = (const unsigned char*)(Wt + (size_t)r * 16384);
    #pragma unroll
    for (int c = 0; c < 8; ++c) {
      int off = c * 4096 + t * 16;
      int row = off >> 8, ib = off & 255;
      *(uint4*)(Bs + row * 256 + (ib ^ ((row & 7) << 4))) = *(const uint4*)(Bsrc + off);
    }
    if (r < 8) {
      float a0[16], a1[16];
      #pragma unroll
      for (int i = 0; i < 16; ++i) { a0[i] = 0.f; a1[i] = 0.f; }
      #pragma unroll
      for (int i = 0; i < 16; ++i) {
        int v = nb + wid * 16 + i;
        if (v < N_NODES) {
          int e0 = rowptr2[(size_t)v * 8 + r], e1 = rowptr2[(size_t)v * 8 + r + 1];
          int e = e0;
          for (; e + 1 < e1; e += 2) {
            unsigned s0 = keys[e], s1 = keys[e + 1];
            unsigned p0 = *(const unsigned*)(hB + ((size_t)s0 << 8) + lane * 4);
            unsigned p1 = *(const unsigned*)(hB + ((size_t)s1 << 8) + lane * 4);
            a0[i] += __uint_as_float(p0 << 16); a1[i] += __uint_as_float(p0 & 0xffff0000u);
            a0[i] += __uint_as_float(p1 << 16); a1[i] += __uint_as_float(p1 & 0xffff0000u);
          }
          if (e < e1) {
            unsigned s0 = keys[e];
            unsigned p0 = *(const unsigned*)(hB + ((size_t)s0 << 8) + lane * 4);
            a0[i] += __uint_as_float(p0 << 16); a1[i] += __uint_as_float(p0 & 0xffff0000u);
          }
        }
      }
      #pragma unroll
      for (int i = 0; i < 16; ++i) {
        int row = wid * 16 + i;
        unsigned pk = ((unsigned)f2bf(a1[i]) << 16) | (unsigned)f2bf(a0[i]);
        *(unsigned*)(As + row * 256 + ((lane * 4) ^ ((row & 7) << 4))) = pk;
      }
    } else {  // self-loop: A row = h[v]
      #pragma unroll
      for (int i = 0; i < 16; ++i) {
        int row = wid * 16 + i;
        int v = nb + row;
        unsigned pk = (v < N_NODES) ? *(const unsigned*)(hB + ((size_t)v << 8) + lane * 4) : 0u;
        *(unsigned*)(As + row * 256 + ((lane * 4) ^ ((row & 7) << 4))) = pk;
      }
    }
    __syncthreads();
    #pragma unroll
    for (int kk = 0; kk < 4; ++kk) {
      int kb = (kk * 32 + kg) * 2;
      int rA = wid * 16 + lr;
      s16x8 a = *(const s16x8*)(As + rA * 256 + (kb ^ ((rA & 7) << 4)));
      #pragma unroll
      for (int n = 0; n < 8; ++n) {
        int cc = n * 16 + lr;
        s16x8 b = *(const s16x8*)(Bs + cc * 256 + (kb ^ ((cc & 7) << 4)));
        C[n] = __builtin_amdgcn_mfma_f32_16x16x32_bf16(a, b, C[n], 0, 0, 0);
      }
    }
    __syncthreads();
  }
  // epilogue: C layout col=lane&15, row=(lane>>4)*4+j
  int rbase = nb + wid * 16 + (lane >> 4) * 4;
  if (LAST) {
    float* o = (float*)out;
    #pragma unroll
    for (int n = 0; n < 8; ++n) {
      int col = n * 16 + lr;
      float bv = bias[col];
      #pragma unroll
      for (int j = 0; j < 4; ++j) {
        int v = rbase + j;
        if (v < N_NODES) o[(size_t)v * 128 + col] = C[n][j] + bv;
      }
    }
  } else {
    unsigned short* o = (unsigned short*)out;
    #pragma unroll
    for (int n = 0; n < 8; ++n) {
      int col = n * 16 + lr;
      float bv = bias[col];
      #pragma unroll
      for (int j = 0; j < 4; ++j) {
        int v = rbase + j;
        if (v < N_NODES) o[(size_t)v * 128 + col] = f2bf(C[n][j] + bv);
      }
    }
  }
}

extern "C" void kernel_launch(void* const* d_in, const int* in_sizes, int n_in,
                              void* d_out, int out_size, void* d_ws, size_t ws_size,
                              hipStream_t stream) {
  const int*   nid  = (const int*)d_in[0];
  const int*   src  = (const int*)d_in[1];
  const int*   dst  = (const int*)d_in[2];
  const int*   et   = (const int*)d_in[3];
  const float* emb  = (const float*)d_in[4];
  const float* W    = (const float*)d_in[5];
  const float* Wl   = (const float*)d_in[6];
  const float* bias = (const float*)d_in[7];

  unsigned char* ws = (unsigned char*)d_ws;
  size_t off = 0;
  auto alloc = [&](size_t bytes) {
    void* p = ws + off;
    off = (off + bytes + 255) & ~(size_t)255;
    return p;
  };
  unsigned short* h0    = (unsigned short*)alloc((size_t)N_NODES * HID * 2);      // 12.8 MB
  unsigned short* h1    = (unsigned short*)alloc((size_t)N_NODES * HID * 2);      // 12.8 MB
  unsigned short* Wt    = (unsigned short*)alloc((size_t)2 * 9 * 128 * 128 * 2);  // 0.6 MB
  unsigned short* keys  = (unsigned short*)alloc((size_t)N_EDGES * 2);            // 3.2 MB
  unsigned*       tmp   = (unsigned*)alloc((size_t)N_EDGES * 4);                  // 6.4 MB
  int*            rowp2 = (int*)alloc(((size_t)N_NODES * 8 + 1) * 4);             // 1.6 MB
  int*            histT = (int*)alloc((size_t)TOT * 4);                           // 150 KB
  int*            cur   = (int*)alloc((size_t)TOT * 4);                           // 150 KB
  int*            bbas  = (int*)alloc((size_t)(NB + 1) * 4);

  k_convert_w<<<1152, 256, 0, stream>>>(W, Wl, Wt);
  k_gather_h0<<<(N_NODES * 32) / 256, 256, 0, stream>>>(nid, emb, h0);
  k_chunk_hist<<<NCH, 256, 0, stream>>>(dst, histT);
  k_csr_scan<<<1, 256, 0, stream>>>(histT, cur, bbas, rowp2);
  k_chunk_scatter<<<NCH, 256, 0, stream>>>(src, dst, et, cur, tmp);
  k_bucket_finalize<<<NB, 256, 0, stream>>>(tmp, bbas, rowp2, keys);

  const int ngrid = (N_NODES + 63) / 64;   // 782
  k_layer<false><<<ngrid, 256, 0, stream>>>(h0, keys, rowp2, Wt, bias, (void*)h1);
  k_layer<true><<<ngrid, 256, 0, stream>>>(h1, keys, rowp2, Wt + (size_t)9 * 128 * 128,
                                           bias + HID, (void*)d_out);
}

// Round 5
// 455.329 us; speedup vs baseline: 2.5466x; 2.5466x over previous
//
#include <hip/hip_runtime.h>
#include <stdint.h>

#define N_NODES 50000
#define N_EDGES 1600000
#define HID 128
#define NB 196      // dst buckets of 256 nodes
#define CHUNK 8192
#define NCH 196     // ceil(1600000 / 8192)
#define TOT (NB * NCH)
#define SCAN_J 152  // ceil(TOT/256)

typedef float f32x4 __attribute__((ext_vector_type(4)));
typedef short s16x8 __attribute__((ext_vector_type(8)));

__device__ __forceinline__ unsigned short f2bf(float f) {
  unsigned u = __float_as_uint(f);
  u += 0x7fffu + ((u >> 16) & 1u);   // RNE
  return (unsigned short)(u >> 16);
}

// ---- W transpose + convert: Wt[l][r][k][d] = W[l][r][d][k] (r=8 -> W_loop) ----
__global__ void k_convert_w(const float* __restrict__ W, const float* __restrict__ Wl,
                            unsigned short* __restrict__ Wt) {
  int idx = blockIdx.x * 256 + threadIdx.x;   // (((l*9+r)*128)+k)*128+d
  int d  = idx & 127;
  int k  = (idx >> 7) & 127;
  int lr = idx >> 14;                          // l*9 + r
  int l = lr / 9, r = lr - l * 9;
  float v;
  if (r < 8) v = W[((((size_t)l * 8 + r) * 128) + d) * 128 + k];
  else       v = Wl[(((size_t)l * 128) + d) * 128 + k];
  Wt[idx] = f2bf(v);
}

// ---- h0 = bf16(emb[node_id]) ----
__global__ void k_gather_h0(const int* __restrict__ nid, const float* __restrict__ emb,
                            unsigned short* __restrict__ h0) {
  int t = blockIdx.x * 256 + threadIdx.x;      // N*32 threads, 4 elems each
  int i = t >> 5, c = (t & 31) * 4;
  if (i >= N_NODES) return;
  const float4 v = *(const float4*)(emb + (size_t)nid[i] * HID + c);
  ushort4 o;
  o.x = f2bf(v.x); o.y = f2bf(v.y); o.z = f2bf(v.z); o.w = f2bf(v.w);
  *(ushort4*)(h0 + (size_t)i * HID + c) = o;
}

__device__ __forceinline__ int block_scan_excl(int v, int t) {
  const int lane = t & 63, wid = t >> 6;
  int incl = v;
  #pragma unroll
  for (int o = 1; o < 64; o <<= 1) {
    int nv = __shfl_up(incl, o);
    if (lane >= o) incl += nv;
  }
  __shared__ int wsum[4];
  if (lane == 63) wsum[wid] = incl;
  __syncthreads();
  int wbase = 0;
  #pragma unroll
  for (int w = 0; w < 3; ++w) if (w < wid) wbase += wsum[w];
  return wbase + incl - v;
}

// ---- CSR pass A: per-chunk bucket histogram -> TRANSPOSED store histT[b][c] ----
__global__ void k_chunk_hist(const int* __restrict__ dst, int* __restrict__ histT) {
  __shared__ int h[NB];
  const int c = blockIdx.x, t = threadIdx.x;
  if (t < NB) h[t] = 0;
  __syncthreads();
  int base = c * CHUNK;
  #pragma unroll 4
  for (int i = t; i < CHUNK; i += 256) {
    int e = base + i;
    if (e < N_EDGES) atomicAdd(&h[dst[e] >> 8], 1);
  }
  __syncthreads();
  if (t < NB) histT[t * NCH + c] = h[t];
}

// ---- CSR pass B: scan 38416 counters (contiguous in bucket-major layout) ----
__global__ void k_csr_scan(const int* __restrict__ histT, int* __restrict__ cur,
                           int* __restrict__ bbase, int* __restrict__ rowptr2) {
  const int t = threadIdx.x;
  const int lo = t * SCAN_J;
  int s = 0;
  #pragma unroll 8
  for (int j = 0; j < SCAN_J; ++j) {
    int idx = lo + j;
    if (idx < TOT) s += histT[idx];
  }
  int run = block_scan_excl(s, t);
  #pragma unroll 4
  for (int j = 0; j < SCAN_J; ++j) {
    int idx = lo + j;                    // idx = b*NCH + c
    if (idx < TOT) {
      int b = idx / NCH, c = idx - b * NCH;
      cur[c * NB + b] = run;
      if (c == 0) bbase[b] = run;
      run += histT[idx];
    }
  }
  if (t == 0) { bbase[NB] = N_EDGES; rowptr2[(size_t)N_NODES * 8] = N_EDGES; }
}

// ---- CSR pass C: chunk-local scatter via LDS cursors (no global atomics) ----
// record = (dst&255)<<19 | et<<16 | src
__global__ void k_chunk_scatter(const int* __restrict__ src, const int* __restrict__ dst,
                                const int* __restrict__ et, const int* __restrict__ cur,
                                unsigned* __restrict__ tmp) {
  __shared__ int off2[NB];
  const int c = blockIdx.x, t = threadIdx.x;
  if (t < NB) off2[t] = cur[c * NB + t];
  __syncthreads();
  int base = c * CHUNK;
  #pragma unroll 4
  for (int i = t; i < CHUNK; i += 256) {
    int e = base + i;
    if (e < N_EDGES) {
      int d = dst[e];
      int pos = atomicAdd(&off2[d >> 8], 1);
      tmp[pos] = ((unsigned)(d & 255) << 19) | ((unsigned)et[e] << 16) | (unsigned)src[e];
    }
  }
}

// ---- CSR finalize: per-(node,rel) counting sort -> rowptr2 + ushort keys ----
__global__ void k_bucket_finalize(const unsigned* __restrict__ tmp,
                                  const int* __restrict__ bbase,
                                  int* __restrict__ rowptr2,
                                  unsigned short* __restrict__ keys) {
  __shared__ int cnt2[2048];
  __shared__ int off2[2048];
  const int b = blockIdx.x;
  const int t = threadIdx.x;
  const int s = bbase[b], e = bbase[b + 1];
  for (int i = t; i < 2048; i += 256) cnt2[i] = 0;
  __syncthreads();
  for (int i = s + t; i < e; i += 256) {
    unsigned r = tmp[i];
    atomicAdd(&cnt2[((r >> 19) & 255u) * 8 + ((r >> 16) & 7u)], 1);
  }
  __syncthreads();
  int v8[8]; int sum = 0;
  #pragma unroll
  for (int j = 0; j < 8; ++j) { v8[j] = cnt2[t * 8 + j]; sum += v8[j]; }
  int ex = block_scan_excl(sum, t);
  int run = s + ex;
  int node = b * 256 + t;
  #pragma unroll
  for (int j = 0; j < 8; ++j) {
    if (node < N_NODES) rowptr2[(size_t)node * 8 + j] = run;
    off2[t * 8 + j] = run;
    run += v8[j];
  }
  __syncthreads();
  for (int i = s + t; i < e; i += 256) {
    unsigned r = tmp[i];
    int pos = atomicAdd(&off2[((r >> 19) & 255u) * 8 + ((r >> 16) & 7u)], 1);
    keys[pos] = (unsigned short)(r & 0xffffu);
  }
}

// ---- per-(node,rel) aggregation: one wave per node, 50K waves ----
// S[r][v][:] = sum_{e in seg(v,r)} h[src_e]   (bf16)
__global__ void k_agg(const unsigned short* __restrict__ h,
                      const unsigned short* __restrict__ keys,
                      const int* __restrict__ rowptr2,
                      unsigned short* __restrict__ S) {
  const int t = threadIdx.x;
  const int v = blockIdx.x * 4 + (t >> 6);
  const int lane = t & 63;
  const unsigned char* hB = (const unsigned char*)h;
  unsigned char* Sb = (unsigned char*)S;
  const int base = v * 8;
  #pragma unroll
  for (int r = 0; r < 8; ++r) {
    const int e0 = rowptr2[base + r], e1 = rowptr2[base + r + 1];
    float a0 = 0.f, a1 = 0.f;
    int e = e0;
    int e4 = e0 + ((e1 - e0) & ~3);
    for (; e < e4; e += 4) {
      unsigned s0 = keys[e], s1 = keys[e + 1], s2 = keys[e + 2], s3 = keys[e + 3];
      unsigned p0 = *(const unsigned*)(hB + ((size_t)s0 << 8) + lane * 4);
      unsigned p1 = *(const unsigned*)(hB + ((size_t)s1 << 8) + lane * 4);
      unsigned p2 = *(const unsigned*)(hB + ((size_t)s2 << 8) + lane * 4);
      unsigned p3 = *(const unsigned*)(hB + ((size_t)s3 << 8) + lane * 4);
      a0 += __uint_as_float(p0 << 16); a1 += __uint_as_float(p0 & 0xffff0000u);
      a0 += __uint_as_float(p1 << 16); a1 += __uint_as_float(p1 & 0xffff0000u);
      a0 += __uint_as_float(p2 << 16); a1 += __uint_as_float(p2 & 0xffff0000u);
      a0 += __uint_as_float(p3 << 16); a1 += __uint_as_float(p3 & 0xffff0000u);
    }
    for (; e < e1; ++e) {
      unsigned s0 = keys[e];
      unsigned p0 = *(const unsigned*)(hB + ((size_t)s0 << 8) + lane * 4);
      a0 += __uint_as_float(p0 << 16); a1 += __uint_as_float(p0 & 0xffff0000u);
    }
    unsigned pk = ((unsigned)f2bf(a1) << 16) | (unsigned)f2bf(a0);
    *(unsigned*)(Sb + (((size_t)r * N_NODES + v) << 8) + lane * 4) = pk;
  }
}

// ---- transform: out = sum_{r<8} S_r @ Wt_r + h @ Wt_8 + bias ----
template <bool LAST>
__global__ __launch_bounds__(256, 3) void k_gemm2(
    const unsigned short* __restrict__ S,    // [8][N][128] bf16
    const unsigned short* __restrict__ h,    // [N][128] bf16
    const unsigned short* __restrict__ Wt,   // [9][128][128] bf16 (this layer)
    const float* __restrict__ bias,
    void* __restrict__ out) {
  __shared__ unsigned char As[64 * 256];   // 16KB
  __shared__ unsigned char Bs[128 * 256];  // 32KB
  const int t = threadIdx.x, wid = t >> 6, lane = t & 63;
  const int nb = blockIdx.x * 64;
  const int lr = lane & 15, kg = (lane >> 4) * 8;
  f32x4 C[8];
  #pragma unroll
  for (int n = 0; n < 8; ++n) C[n] = (f32x4)(0.f);

  for (int r = 0; r < 9; ++r) {
    const unsigned char* Asrc = (r < 8)
        ? (const unsigned char*)(S + (size_t)r * N_NODES * 128)
        : (const unsigned char*)h;
    // stage A-tile (16KB): rows nb..nb+63, swizzled
    #pragma unroll
    for (int c = 0; c < 4; ++c) {
      int off = c * 4096 + t * 16;
      int row = off >> 8, ib = off & 255;
      int grow = nb + row;
      uint4 va = make_uint4(0u, 0u, 0u, 0u);
      if (grow < N_NODES) va = *(const uint4*)(Asrc + (size_t)grow * 256 + ib);
      *(uint4*)(As + row * 256 + (ib ^ ((row & 7) << 4))) = va;
    }
    // stage B = Wt_r (32KB), swizzled
    const unsigned char* Bsrc = (const unsigned char*)(Wt + (size_t)r * 16384);
    #pragma unroll
    for (int c = 0; c < 8; ++c) {
      int off = c * 4096 + t * 16;
      int row = off >> 8, ib = off & 255;
      *(uint4*)(Bs + row * 256 + (ib ^ ((row & 7) << 4))) = *(const uint4*)(Bsrc + off);
    }
    __syncthreads();
    #pragma unroll
    for (int kk = 0; kk < 4; ++kk) {
      int kb = (kk * 32 + kg) * 2;
      int rA = wid * 16 + lr;
      s16x8 a = *(const s16x8*)(As + rA * 256 + (kb ^ ((rA & 7) << 4)));
      #pragma unroll
      for (int n = 0; n < 8; ++n) {
        int cc = n * 16 + lr;
        s16x8 b = *(const s16x8*)(Bs + cc * 256 + (kb ^ ((cc & 7) << 4)));
        C[n] = __builtin_amdgcn_mfma_f32_16x16x32_bf16(a, b, C[n], 0, 0, 0);
      }
    }
    __syncthreads();
  }
  // epilogue: C layout col=lane&15, row=(lane>>4)*4+j
  const int rbase = nb + wid * 16 + (lane >> 4) * 4;
  if (LAST) {
    float* o = (float*)out;
    #pragma unroll
    for (int n = 0; n < 8; ++n) {
      int col = n * 16 + lr;
      float bv = bias[col];
      #pragma unroll
      for (int j = 0; j < 4; ++j) {
        int v = rbase + j;
        if (v < N_NODES) o[(size_t)v * 128 + col] = C[n][j] + bv;
      }
    }
  } else {
    unsigned short* o = (unsigned short*)out;
    #pragma unroll
    for (int n = 0; n < 8; ++n) {
      int col = n * 16 + lr;
      float bv = bias[col];
      #pragma unroll
      for (int j = 0; j < 4; ++j) {
        int v = rbase + j;
        if (v < N_NODES) o[(size_t)v * 128 + col] = f2bf(C[n][j] + bv);
      }
    }
  }
}

extern "C" void kernel_launch(void* const* d_in, const int* in_sizes, int n_in,
                              void* d_out, int out_size, void* d_ws, size_t ws_size,
                              hipStream_t stream) {
  const int*   nid  = (const int*)d_in[0];
  const int*   src  = (const int*)d_in[1];
  const int*   dst  = (const int*)d_in[2];
  const int*   et   = (const int*)d_in[3];
  const float* emb  = (const float*)d_in[4];
  const float* W    = (const float*)d_in[5];
  const float* Wl   = (const float*)d_in[6];
  const float* bias = (const float*)d_in[7];

  unsigned char* ws = (unsigned char*)d_ws;
  size_t off = 0;
  auto alloc = [&](size_t bytes) {
    void* p = ws + off;
    off = (off + bytes + 255) & ~(size_t)255;
    return p;
  };
  unsigned short* S     = (unsigned short*)alloc((size_t)8 * N_NODES * HID * 2);  // 102.4 MB
  unsigned short* h0    = (unsigned short*)alloc((size_t)N_NODES * HID * 2);      // 12.8 MB
  unsigned short* h1    = (unsigned short*)alloc((size_t)N_NODES * HID * 2);      // 12.8 MB
  unsigned short* Wt    = (unsigned short*)alloc((size_t)2 * 9 * 128 * 128 * 2);  // 0.6 MB
  unsigned short* keys  = (unsigned short*)alloc((size_t)N_EDGES * 2);            // 3.2 MB
  unsigned*       tmp   = (unsigned*)S;    // S dead during CSR build; reuse as scratch
  int*            rowp2 = (int*)alloc(((size_t)N_NODES * 8 + 1) * 4);             // 1.6 MB
  int*            histT = (int*)alloc((size_t)TOT * 4);                           // 150 KB
  int*            cur   = (int*)alloc((size_t)TOT * 4);                           // 150 KB
  int*            bbas  = (int*)alloc((size_t)(NB + 1) * 4);

  k_convert_w<<<1152, 256, 0, stream>>>(W, Wl, Wt);
  k_gather_h0<<<(N_NODES * 32) / 256, 256, 0, stream>>>(nid, emb, h0);
  k_chunk_hist<<<NCH, 256, 0, stream>>>(dst, histT);
  k_csr_scan<<<1, 256, 0, stream>>>(histT, cur, bbas, rowp2);
  k_chunk_scatter<<<NCH, 256, 0, stream>>>(src, dst, et, cur, tmp);
  k_bucket_finalize<<<NB, 256, 0, stream>>>(tmp, bbas, rowp2, keys);

  const int agrid = N_NODES / 4;                 // 12500, one wave per node
  const int ggrid = (N_NODES + 63) / 64;         // 782
  // layer 0
  k_agg<<<agrid, 256, 0, stream>>>(h0, keys, rowp2, S);
  k_gemm2<false><<<ggrid, 256, 0, stream>>>(S, h0, Wt, bias, (void*)h1);
  // layer 1
  k_agg<<<agrid, 256, 0, stream>>>(h1, keys, rowp2, S);
  k_gemm2<true><<<ggrid, 256, 0, stream>>>(S, h1, Wt + (size_t)9 * 128 * 128,
                                           bias + HID, (void*)d_out);
}